// Round 13
// baseline (262.761 us; speedup 1.0000x reference)
//
#include <hip/hip_runtime.h>
#include <hip/hip_bf16.h>
#include <math.h>

#define TOK   4096
#define EDIM  512
#define HEADS 8
#define DHEAD 64

typedef __attribute__((ext_vector_type(8))) short short8v;
typedef __attribute__((ext_vector_type(4))) float float4v;
typedef __attribute__((ext_vector_type(4))) unsigned int uint4v;

#define SC2 0.180336880111f   /* 0.125 * log2(e) */

__device__ __forceinline__ unsigned short f2bf(float f) {
    unsigned int u = __float_as_uint(f);
    unsigned int r = (u + 0x7FFFu + ((u >> 16) & 1u)) >> 16;
    return (unsigned short)r;
}
// pack (truncating) bf16(lo) | bf16(hi)<<16 in one v_perm_b32
__device__ __forceinline__ unsigned int packbf_tr(float lo, float hi) {
    return __builtin_amdgcn_perm(__float_as_uint(hi), __float_as_uint(lo), 0x07060302u);
}
__device__ __forceinline__ float fast_exp2(float x) {
#if __has_builtin(__builtin_amdgcn_exp2f)
    return __builtin_amdgcn_exp2f(x);
#else
    return __expf(x * 0.69314718f);
#endif
}
// barrier with LDS-only drain: does NOT retire outstanding global stores/loads.
// 0xC07F = vmcnt(63) expcnt(7) lgkmcnt(0) on gfx9-encoding waitcnt.
__device__ __forceinline__ void soft_barrier() {
    __builtin_amdgcn_sched_barrier(0);
    __builtin_amdgcn_s_waitcnt(0xC07F);
    __builtin_amdgcn_s_barrier();
    __builtin_amdgcn_sched_barrier(0);
}

// ---------------------------------------------------------------------------
// prep: convert x and the 4 weight matrices to bf16 (one kernel).
// ---------------------------------------------------------------------------
__global__ __launch_bounds__(256) void to_bf16_all(
    const float* __restrict__ x,
    const float* __restrict__ wq, const float* __restrict__ wk,
    const float* __restrict__ wv, const float* __restrict__ wo,
    unsigned short* __restrict__ xb,
    unsigned short* __restrict__ wqb, unsigned short* __restrict__ wkb,
    unsigned short* __restrict__ wvb, unsigned short* __restrict__ wob)
{
    const int bid = blockIdx.x;
    const float* src; unsigned short* dst; int idx;
    if (bid < 1024) { src = x; dst = xb; idx = bid; }
    else {
        const int k = (bid - 1024) >> 7;
        idx = (bid - 1024) & 127;
        src = (k == 0) ? wq : (k == 1) ? wk : (k == 2) ? wv : wo;
        dst = (k == 0) ? wqb : (k == 1) ? wkb : (k == 2) ? wvb : wob;
    }
    const int off = idx * 2048 + threadIdx.x * 8;
    float4 a = *(const float4*)(src + off);
    float4 b = *(const float4*)(src + off + 4);
    short8v o;
    o[0] = (short)f2bf(a.x); o[1] = (short)f2bf(a.y);
    o[2] = (short)f2bf(a.z); o[3] = (short)f2bf(a.w);
    o[4] = (short)f2bf(b.x); o[5] = (short)f2bf(b.y);
    o[6] = (short)f2bf(b.z); o[7] = (short)f2bf(b.w);
    *(short8v*)(dst + off) = o;
}

// ---------------------------------------------------------------------------
// bf16 MFMA GEMM (verified R4-R12): Y = A @ W^T + bias, 64x64 tile, BK=64,
// double-buffered LDS, 1 barrier per k-step.
// MODE 0: none; 1: also bf16 sec[h][m][d]; 2: also bf16 sec[h][d][m].
// ---------------------------------------------------------------------------
template<int MODE>
__global__ __launch_bounds__(256, 3) void gemm512(
    const unsigned short* __restrict__ A,
    const unsigned short* __restrict__ W,
    const float* __restrict__ bias,
    float* __restrict__ Y,
    unsigned short* __restrict__ sec)
{
    __shared__ alignas(16) char sA[2][8192];
    __shared__ alignas(16) char sB[2][8192];

    const int t = threadIdx.x;
    const int lane = t & 63, w = t >> 6;
    const int l15 = lane & 15, g4 = lane >> 4;
    const int wr = w >> 1, wc = w & 1;
    const int m0 = blockIdx.y * 64, n0 = blockIdx.x * 64;

    short8v areg[2], breg[2];

#define GL(kk) { _Pragma("unroll") for (int j = 0; j < 2; ++j) { \
        const int unit_ = j * 256 + t, row_ = unit_ >> 3, u_ = unit_ & 7; \
        areg[j] = *(const short8v*)(A + (size_t)(m0 + row_) * 512 + (kk) * 64 + u_ * 8); \
        breg[j] = *(const short8v*)(W + (size_t)(n0 + row_) * 512 + (kk) * 64 + u_ * 8); } }
#define GW(b) { _Pragma("unroll") for (int j = 0; j < 2; ++j) { \
        const int unit_ = j * 256 + t, row_ = unit_ >> 3, u_ = unit_ & 7; \
        const int byt_ = row_ * 128 + ((u_ ^ (row_ & 7)) * 16); \
        *(short8v*)(sA[b] + byt_) = areg[j]; *(short8v*)(sB[b] + byt_) = breg[j]; } }

    float4v acc[2][2];
#pragma unroll
    for (int mi = 0; mi < 2; ++mi)
#pragma unroll
        for (int ni = 0; ni < 2; ++ni) acc[mi][ni] = (float4v){0.f, 0.f, 0.f, 0.f};

    GL(0); GW(0); __syncthreads();

#pragma unroll 2
    for (int kk = 0; kk < 8; ++kk) {
        if (kk < 7) GL(kk + 1);
        const char* cA = sA[kk & 1];
        const char* cB = sB[kk & 1];
        short8v af[2][2], bf[2][2];
#pragma unroll
        for (int mi = 0; mi < 2; ++mi)
#pragma unroll
            for (int kh = 0; kh < 2; ++kh) {
                const int row = wr * 32 + mi * 16 + l15;
                af[mi][kh] = *(const short8v*)(cA + row * 128 + (((kh * 4 + g4) ^ (l15 & 7)) * 16));
            }
#pragma unroll
        for (int ni = 0; ni < 2; ++ni)
#pragma unroll
            for (int kh = 0; kh < 2; ++kh) {
                const int row = wc * 32 + ni * 16 + l15;
                bf[ni][kh] = *(const short8v*)(cB + row * 128 + (((kh * 4 + g4) ^ (l15 & 7)) * 16));
            }
        __builtin_amdgcn_s_setprio(1);
#pragma unroll
        for (int mi = 0; mi < 2; ++mi)
#pragma unroll
            for (int ni = 0; ni < 2; ++ni) {
                acc[mi][ni] = __builtin_amdgcn_mfma_f32_16x16x32_bf16(af[mi][0], bf[ni][0], acc[mi][ni], 0, 0, 0);
                acc[mi][ni] = __builtin_amdgcn_mfma_f32_16x16x32_bf16(af[mi][1], bf[ni][1], acc[mi][ni], 0, 0, 0);
            }
        __builtin_amdgcn_s_setprio(0);
        if (kk < 7) GW((kk + 1) & 1);
        __syncthreads();
    }

#pragma unroll
    for (int mi = 0; mi < 2; ++mi)
#pragma unroll
        for (int ni = 0; ni < 2; ++ni) {
            const int col = n0 + wc * 32 + ni * 16 + l15;
            const float bb = bias[col];
#pragma unroll
            for (int r = 0; r < 4; ++r) {
                const int row = m0 + wr * 32 + mi * 16 + g4 * 4 + r;
                const float v = acc[mi][ni][r] + bb;
                Y[(size_t)row * 512 + col] = v;
                if (MODE == 1)
                    sec[((size_t)(col >> 6) * TOK + row) * 64 + (col & 63)] = f2bf(v);
                if (MODE == 2)
                    sec[((size_t)(col >> 6) * 64 + (col & 63)) * TOK + row] = f2bf(v);
            }
        }
#undef GL
#undef GW
}

// ---------------------------------------------------------------------------
// fused attention == R12 (verified 204.5us) with ONE change: pass 1 reads K
// DIRECTLY from L2 via static reg double-buffer (R10-verified addressing) --
// no pass-1 LDS staging, no pass-1 barriers.  Pass 2 and epilogue identical.
// Block = 32 q-rows x 1 head, 4 waves, grid 1024, 4 blocks/CU (LDS 40960B,
// VGPR <= 128 via __launch_bounds__(256,4) -> 16 waves/CU).
// Wave w: row-group rg = w>>1 (16 rows), m-half mh = w&1 of each 128-m chunk.
// ---------------------------------------------------------------------------
__global__ __launch_bounds__(256, 4) void fused_attn(
    const float* __restrict__ Q,             // [TOK][EDIM] f32
    const unsigned short* __restrict__ Kb,   // [H][TOK][64] bf16
    const unsigned short* __restrict__ Vt,   // [H][64][TOK] bf16
    float* __restrict__ attn,                // [H][TOK][TOK] f32
    unsigned short* __restrict__ ctxb)       // [TOK][EDIM] bf16
{
    // pass2: sK 16KB + sV 16KB | transient redS | epilogue: O partials
    __shared__ alignas(16) char lds_main[32768];
    __shared__ alignas(16) char ldsP[8192];     // 4 waves x [16 rows][128B] P tiles

    const int t = threadIdx.x;
    const int lane = t & 63, w = t >> 6;
    const int l15 = lane & 15, g4 = lane >> 4;
    const int bid = blockIdx.x;
    const int h  = bid & 7;                  // head-per-XCD L2 locality
    const int n0 = (bid >> 3) * 32;
    const int rg = w >> 1;                   // row-group (16 rows)
    const int mh = w & 1;                    // m-half of each 128-chunk
    const int xsw = (l15 & 7) << 1;          // P-LDS swizzle (8B-slot XOR)

    const unsigned short* KbH = Kb + (size_t)h * TOK * DHEAD;
    const unsigned short* VtH = Vt + (size_t)h * DHEAD * TOK;
    char* myP = ldsP + w * 2048;             // [16 rows][16 slot8] bf16
    float* redS = (float*)lds_main;          // [32 rows][2 halves] (transient)

    // ---- Q B-fragment for this wave's 16 rows (col n=l15, k d=g4*8+j) ----
    short8v bq[2];
    {
        const float* qp = Q + (size_t)(n0 + rg * 16 + l15) * EDIM + h * DHEAD + g4 * 8;
#pragma unroll
        for (int ks = 0; ks < 2; ++ks) {
            float4 u = *(const float4*)(qp + ks * 32);
            float4 v = *(const float4*)(qp + ks * 32 + 4);
            bq[ks][0] = (short)f2bf(u.x); bq[ks][1] = (short)f2bf(u.y);
            bq[ks][2] = (short)f2bf(u.z); bq[ks][3] = (short)f2bf(u.w);
            bq[ks][4] = (short)f2bf(v.x); bq[ks][5] = (short)f2bf(v.y);
            bq[ks][6] = (short)f2bf(v.z); bq[ks][7] = (short)f2bf(v.w);
        }
    }

    // ================= pass 1: row sums (K direct from L2, no barriers) ======
    // wave covers m = c*128 + mh*64 + [0,64) for c = 0..31  (R10-verified)
    float psum = 0.f;
#define LOADKD(buf, c) { _Pragma("unroll") for (int mt_ = 0; mt_ < 4; ++mt_) \
        _Pragma("unroll") for (int ks_ = 0; ks_ < 2; ++ks_) \
        buf[mt_][ks_] = *(const short8v*)(KbH + \
            (size_t)((c) * 128 + mh * 64 + mt_ * 16 + l15) * 64 + ks_ * 32 + g4 * 8); }
#define SUMCHUNK(kab) { _Pragma("unroll") for (int mt = 0; mt < 4; ++mt) { \
            __builtin_amdgcn_s_setprio(1); \
            float4v s = (float4v){0.f, 0.f, 0.f, 0.f}; \
            s = __builtin_amdgcn_mfma_f32_16x16x32_bf16(kab[mt][0], bq[0], s, 0, 0, 0); \
            s = __builtin_amdgcn_mfma_f32_16x16x32_bf16(kab[mt][1], bq[1], s, 0, 0, 0); \
            __builtin_amdgcn_s_setprio(0); \
            _Pragma("unroll") for (int r = 0; r < 4; ++r) \
                psum += fast_exp2(s[r] * SC2); } }
    {
        short8v kaA[4][2], kaB[4][2];
        LOADKD(kaA, 0)
        for (int c = 0; c < 32; c += 2) {
            LOADKD(kaB, c + 1)
            SUMCHUNK(kaA)
            if (c < 30) LOADKD(kaA, c + 2)
            SUMCHUNK(kaB)
        }
    }
#undef LOADKD
#undef SUMCHUNK
    // reduce over g4 (lanes sharing row n), publish per (row, m-half)
    psum += __shfl_xor(psum, 16, 64);
    psum += __shfl_xor(psum, 32, 64);
    if (lane < 16)
        redS[(rg * 16 + lane) * 2 + mh] = psum;
    __syncthreads();
    const float inv = 1.0f / (redS[(rg * 16 + l15) * 2] + redS[(rg * 16 + l15) * 2 + 1]);
    __syncthreads();                          // redS consumed; lds_main reusable

    // ================= pass 2: attn store + PV (identical to R12) ============
    float* aH = attn + ((size_t)h * TOK + n0 + rg * 16 + l15) * TOK;
    float4v cacc[4];
#pragma unroll
    for (int dt = 0; dt < 4; ++dt) cacc[dt] = (float4v){0.f, 0.f, 0.f, 0.f};

    short8v kreg[4], vreg[4];
    char* sK2 = lds_main;
    char* sV2 = lds_main + 16384;

    // K chunk [128 m][64 d] staged by all 256 threads (4 x 16B each)
#define LK(c) { _Pragma("unroll") for (int j = 0; j < 4; ++j) { \
        const int unit_ = j * 256 + t, row_ = unit_ >> 3, u_ = unit_ & 7; \
        kreg[j] = *(const short8v*)(KbH + (size_t)((c) * 128 + row_) * 64 + u_ * 8); } }
#define WK(base) { _Pragma("unroll") for (int j = 0; j < 4; ++j) { \
        const int unit_ = j * 256 + t, row_ = unit_ >> 3, u_ = unit_ & 7; \
        *(short8v*)((base) + row_ * 128 + ((u_ ^ (row_ & 7)) * 16)) = kreg[j]; } }
    // V chunk [64 d][128 m]
#define LV(c) { _Pragma("unroll") for (int j = 0; j < 4; ++j) { \
        const int unit_ = j * 256 + t, row_ = unit_ >> 4, u_ = unit_ & 15; \
        vreg[j] = *(const short8v*)(VtH + (size_t)row_ * TOK + (c) * 128 + u_ * 8); } }
#define WV(base) { _Pragma("unroll") for (int j = 0; j < 4; ++j) { \
        const int unit_ = j * 256 + t, row_ = unit_ >> 4, u_ = unit_ & 15; \
        *(short8v*)((base) + row_ * 256 + ((u_ ^ (row_ & 7)) * 16)) = vreg[j]; } }

    LK(0); LV(0); WK(sK2); WV(sV2); __syncthreads();
    for (int c = 0; c < 32; ++c) {
        if (c < 31) { LK(c + 1); LV(c + 1); }
        const int mbase = c * 128 + mh * 64;
#pragma unroll
        for (int mt = 0; mt < 4; ++mt) {
            const int row = mh * 64 + mt * 16 + l15;
            short8v k0 = *(const short8v*)(sK2 + row * 128 + ((g4 ^ (l15 & 7)) * 16));
            short8v k1 = *(const short8v*)(sK2 + row * 128 + (((4 + g4) ^ (l15 & 7)) * 16));
            __builtin_amdgcn_s_setprio(1);
            float4v s = (float4v){0.f, 0.f, 0.f, 0.f};
            s = __builtin_amdgcn_mfma_f32_16x16x32_bf16(k0, bq[0], s, 0, 0, 0);
            s = __builtin_amdgcn_mfma_f32_16x16x32_bf16(k1, bq[1], s, 0, 0, 0);
            __builtin_amdgcn_s_setprio(0);
            float4v p;
#pragma unroll
            for (int r = 0; r < 4; ++r)
                p[r] = fast_exp2(s[r] * SC2) * inv;
            *(float4v*)(aH + mbase + mt * 16 + g4 * 4) = p;   // plain store
            const unsigned int u0 = packbf_tr(p[0], p[1]);
            const unsigned int u1 = packbf_tr(p[2], p[3]);
            *(uint2*)(myP + l15 * 128 + (((mt * 4 + g4) ^ xsw) << 3)) =
                make_uint2(u0, u1);
        }
        // PV over this wave's 64-m half: A=P[n=l15][k], B=V[d][k]
        __builtin_amdgcn_s_setprio(1);
#pragma unroll
        for (int ks2 = 0; ks2 < 2; ++ks2) {
            const uint4v pr = *(const uint4v*)(myP + l15 * 128 +
                                               (((ks2 * 8 + g4 * 2) ^ xsw) << 3));
            const short8v pa = __builtin_bit_cast(short8v, pr);
#pragma unroll
            for (int dt = 0; dt < 4; ++dt) {
                const int rowv = dt * 16 + l15;
                const int uu = (mh * 8 + ks2 * 4 + g4) ^ (l15 & 7);
                short8v vf = *(const short8v*)(sV2 + rowv * 256 + uu * 16);
                cacc[dt] = __builtin_amdgcn_mfma_f32_16x16x32_bf16(pa, vf, cacc[dt], 0, 0, 0);
            }
        }
        __builtin_amdgcn_s_setprio(0);
        soft_barrier();
        if (c < 31) { WK(sK2); WV(sV2); soft_barrier(); }
    }

    // ---- pairwise cross-wave O reduction (lds_main free; stride-68 f32) ----
    __syncthreads();
    float* osh = (float*)lds_main + (size_t)w * 1088;   // [16 rows][68]
#pragma unroll
    for (int dt = 0; dt < 4; ++dt)
#pragma unroll
        for (int r = 0; r < 4; ++r)
            osh[(g4 * 4 + r) * 68 + dt * 16 + l15] = cacc[dt][r];
    __syncthreads();
    {
        const int n = t >> 3, dq = t & 7;               // 32 rows x 8 d-octets
        const int w0 = (n >> 4) * 2;                    // waves holding this row
        const float* o0 = (const float*)lds_main + (size_t)w0 * 1088 + (n & 15) * 68 + dq * 8;
        unsigned short ob[8];
#pragma unroll
        for (int q = 0; q < 2; ++q) {
            float4 s = *(const float4*)(o0 + q * 4);
            const float4 a = *(const float4*)(o0 + 1088 + q * 4);
            s.x += a.x; s.y += a.y; s.z += a.z; s.w += a.w;
            ob[q * 4 + 0] = f2bf(s.x); ob[q * 4 + 1] = f2bf(s.y);
            ob[q * 4 + 2] = f2bf(s.z); ob[q * 4 + 3] = f2bf(s.w);
        }
        *(short8v*)(ctxb + (size_t)(n0 + n) * EDIM + h * DHEAD + dq * 8) =
            *(const short8v*)&ob[0];
    }
#undef LK
#undef WK
#undef LV
#undef WV
}

// ---------------------------------------------------------------------------
// launch
// ---------------------------------------------------------------------------
extern "C" void kernel_launch(void* const* d_in, const int* in_sizes, int n_in,
                              void* d_out, int out_size, void* d_ws, size_t ws_size,
                              hipStream_t stream) {
    (void)in_sizes; (void)n_in; (void)out_size; (void)ws_size;

    const float* x  = (const float*)d_in[0];
    const float* Wq = (const float*)d_in[1];
    const float* bq = (const float*)d_in[2];
    const float* Wk = (const float*)d_in[3];
    const float* bk = (const float*)d_in[4];
    const float* Wv = (const float*)d_in[5];
    const float* bv = (const float*)d_in[6];
    const float* Wo = (const float*)d_in[7];
    const float* bo = (const float*)d_in[8];

    float* out  = (float*)d_out;                       // [TOK, EDIM]
    float* attn = out  + (size_t)TOK * EDIM;           // [H, TOK, TOK]
    float* Qf   = attn + (size_t)HEADS * TOK * TOK;    // [TOK, EDIM]
    float* Kf   = Qf   + (size_t)TOK * EDIM;
    float* Vf   = Kf   + (size_t)TOK * EDIM;

    char* wsb = (char*)d_ws;
    unsigned short* xb   = (unsigned short*)wsb;                     // 4 MB (reused as ctxb)
    unsigned short* wqb  = (unsigned short*)(wsb + (4u << 20));
    unsigned short* wkb  = (unsigned short*)(wsb + (4u << 20) + (512u << 10));
    unsigned short* wvb  = (unsigned short*)(wsb + (5u << 20));
    unsigned short* wob  = (unsigned short*)(wsb + (5u << 20) + (512u << 10));
    unsigned short* KbW  = (unsigned short*)(wsb + (6u << 20));      // 4 MB
    unsigned short* VtW  = (unsigned short*)(wsb + (10u << 20));     // 4 MB
    unsigned short* ctxb = xb;

    to_bf16_all<<<1536, 256, 0, stream>>>(x, Wq, Wk, Wv, Wo, xb, wqb, wkb, wvb, wob);

    dim3 gg(EDIM / 64, TOK / 64);
    gemm512<0><<<gg, 256, 0, stream>>>(xb, wqb, bq, Qf, nullptr);
    gemm512<1><<<gg, 256, 0, stream>>>(xb, wkb, bk, Kf, KbW);
    gemm512<2><<<gg, 256, 0, stream>>>(xb, wvb, bv, Vf, VtW);

    fused_attn<<<1024, 256, 0, stream>>>(Qf, KbW, VtW, attn, ctxb);

    gemm512<0><<<gg, 256, 0, stream>>>(ctxb, wob, bo, out, nullptr);
}

// Round 14
// 229.312 us; speedup vs baseline: 1.1459x; 1.1459x over previous
//
#include <hip/hip_runtime.h>
#include <hip/hip_bf16.h>
#include <math.h>

#define TOK   4096
#define EDIM  512
#define HEADS 8
#define DHEAD 64

typedef __attribute__((ext_vector_type(8))) short short8v;
typedef __attribute__((ext_vector_type(4))) float float4v;
typedef __attribute__((ext_vector_type(4))) unsigned int uint4v;

#define SC2 0.180336880111f   /* 0.125 * log2(e) */

__device__ __forceinline__ unsigned short f2bf(float f) {
    unsigned int u = __float_as_uint(f);
    unsigned int r = (u + 0x7FFFu + ((u >> 16) & 1u)) >> 16;
    return (unsigned short)r;
}
// pack (truncating) bf16(lo) | bf16(hi)<<16 in one v_perm_b32
__device__ __forceinline__ unsigned int packbf_tr(float lo, float hi) {
    return __builtin_amdgcn_perm(__float_as_uint(hi), __float_as_uint(lo), 0x07060302u);
}
__device__ __forceinline__ float fast_exp2(float x) {
#if __has_builtin(__builtin_amdgcn_exp2f)
    return __builtin_amdgcn_exp2f(x);
#else
    return __expf(x * 0.69314718f);
#endif
}
// barrier with LDS-only drain: does NOT retire outstanding global stores/loads.
// 0xC07F = vmcnt(63) expcnt(7) lgkmcnt(0) on gfx9-encoding waitcnt.
__device__ __forceinline__ void soft_barrier() {
    __builtin_amdgcn_sched_barrier(0);
    __builtin_amdgcn_s_waitcnt(0xC07F);
    __builtin_amdgcn_s_barrier();
    __builtin_amdgcn_sched_barrier(0);
}

// ---------------------------------------------------------------------------
// prep: convert x and the 4 weight matrices to bf16 (one kernel).
// ---------------------------------------------------------------------------
__global__ __launch_bounds__(256) void to_bf16_all(
    const float* __restrict__ x,
    const float* __restrict__ wq, const float* __restrict__ wk,
    const float* __restrict__ wv, const float* __restrict__ wo,
    unsigned short* __restrict__ xb,
    unsigned short* __restrict__ wqb, unsigned short* __restrict__ wkb,
    unsigned short* __restrict__ wvb, unsigned short* __restrict__ wob)
{
    const int bid = blockIdx.x;
    const float* src; unsigned short* dst; int idx;
    if (bid < 1024) { src = x; dst = xb; idx = bid; }
    else {
        const int k = (bid - 1024) >> 7;
        idx = (bid - 1024) & 127;
        src = (k == 0) ? wq : (k == 1) ? wk : (k == 2) ? wv : wo;
        dst = (k == 0) ? wqb : (k == 1) ? wkb : (k == 2) ? wvb : wob;
    }
    const int off = idx * 2048 + threadIdx.x * 8;
    float4 a = *(const float4*)(src + off);
    float4 b = *(const float4*)(src + off + 4);
    short8v o;
    o[0] = (short)f2bf(a.x); o[1] = (short)f2bf(a.y);
    o[2] = (short)f2bf(a.z); o[3] = (short)f2bf(a.w);
    o[4] = (short)f2bf(b.x); o[5] = (short)f2bf(b.y);
    o[6] = (short)f2bf(b.z); o[7] = (short)f2bf(b.w);
    *(short8v*)(dst + off) = o;
}

// ---------------------------------------------------------------------------
// Shared GEMM body (verified R4-R13 structure): Y = A @ W^T + bias.
// mode 0: plain; 1: also bf16 sec[h][m][d]; 2: also bf16 sec[h][d][m].
// ---------------------------------------------------------------------------
__device__ __forceinline__ void gemm_body(
    const unsigned short* __restrict__ A,
    const unsigned short* __restrict__ W,
    const float* __restrict__ bias,
    float* __restrict__ Y,
    unsigned short* __restrict__ sec,
    int mode, int m0, int n0,
    char* sA0, char* sA1, char* sB0, char* sB1)
{
    const int t = threadIdx.x;
    const int lane = t & 63, w = t >> 6;
    const int l15 = lane & 15, g4 = lane >> 4;
    const int wr = w >> 1, wc = w & 1;

    short8v areg[2], breg[2];
    char* sA[2] = {sA0, sA1};
    char* sB[2] = {sB0, sB1};

#define GL(kk) { _Pragma("unroll") for (int j = 0; j < 2; ++j) { \
        const int unit_ = j * 256 + t, row_ = unit_ >> 3, u_ = unit_ & 7; \
        areg[j] = *(const short8v*)(A + (size_t)(m0 + row_) * 512 + (kk) * 64 + u_ * 8); \
        breg[j] = *(const short8v*)(W + (size_t)(n0 + row_) * 512 + (kk) * 64 + u_ * 8); } }
#define GW(b) { _Pragma("unroll") for (int j = 0; j < 2; ++j) { \
        const int unit_ = j * 256 + t, row_ = unit_ >> 3, u_ = unit_ & 7; \
        const int byt_ = row_ * 128 + ((u_ ^ (row_ & 7)) * 16); \
        *(short8v*)(sA[b] + byt_) = areg[j]; *(short8v*)(sB[b] + byt_) = breg[j]; } }

    float4v acc[2][2];
#pragma unroll
    for (int mi = 0; mi < 2; ++mi)
#pragma unroll
        for (int ni = 0; ni < 2; ++ni) acc[mi][ni] = (float4v){0.f, 0.f, 0.f, 0.f};

    GL(0); GW(0); __syncthreads();

#pragma unroll 2
    for (int kk = 0; kk < 8; ++kk) {
        if (kk < 7) GL(kk + 1);
        const char* cA = sA[kk & 1];
        const char* cB = sB[kk & 1];
        short8v af[2][2], bf[2][2];
#pragma unroll
        for (int mi = 0; mi < 2; ++mi)
#pragma unroll
            for (int kh = 0; kh < 2; ++kh) {
                const int row = wr * 32 + mi * 16 + l15;
                af[mi][kh] = *(const short8v*)(cA + row * 128 + (((kh * 4 + g4) ^ (l15 & 7)) * 16));
            }
#pragma unroll
        for (int ni = 0; ni < 2; ++ni)
#pragma unroll
            for (int kh = 0; kh < 2; ++kh) {
                const int row = wc * 32 + ni * 16 + l15;
                bf[ni][kh] = *(const short8v*)(cB + row * 128 + (((kh * 4 + g4) ^ (l15 & 7)) * 16));
            }
        __builtin_amdgcn_s_setprio(1);
#pragma unroll
        for (int mi = 0; mi < 2; ++mi)
#pragma unroll
            for (int ni = 0; ni < 2; ++ni) {
                acc[mi][ni] = __builtin_amdgcn_mfma_f32_16x16x32_bf16(af[mi][0], bf[ni][0], acc[mi][ni], 0, 0, 0);
                acc[mi][ni] = __builtin_amdgcn_mfma_f32_16x16x32_bf16(af[mi][1], bf[ni][1], acc[mi][ni], 0, 0, 0);
            }
        __builtin_amdgcn_s_setprio(0);
        if (kk < 7) GW((kk + 1) & 1);
        __syncthreads();
    }

#pragma unroll
    for (int mi = 0; mi < 2; ++mi)
#pragma unroll
        for (int ni = 0; ni < 2; ++ni) {
            const int col = n0 + wc * 32 + ni * 16 + l15;
            const float bb = bias[col];
#pragma unroll
            for (int r = 0; r < 4; ++r) {
                const int row = m0 + wr * 32 + mi * 16 + g4 * 4 + r;
                const float v = acc[mi][ni][r] + bb;
                Y[(size_t)row * 512 + col] = v;
                if (mode == 1)
                    sec[((size_t)(col >> 6) * TOK + row) * 64 + (col & 63)] = f2bf(v);
                else if (mode == 2)
                    sec[((size_t)(col >> 6) * 64 + (col & 63)) * TOK + row] = f2bf(v);
            }
        }
#undef GL
#undef GW
}

// ---------------------------------------------------------------------------
// merged Q/K/V projection: blockIdx.z selects which of the three GEMMs.
// 1536 blocks resident at once (vs 3 serial 512-block launches).
// ---------------------------------------------------------------------------
__global__ __launch_bounds__(256, 3) void gemm_qkv(
    const unsigned short* __restrict__ xb,
    const unsigned short* __restrict__ wqb,
    const unsigned short* __restrict__ wkb,
    const unsigned short* __restrict__ wvb,
    const float* __restrict__ bq, const float* __restrict__ bk,
    const float* __restrict__ bv,
    float* __restrict__ Qf, float* __restrict__ Kf, float* __restrict__ Vf,
    unsigned short* __restrict__ KbW, unsigned short* __restrict__ VtW)
{
    __shared__ alignas(16) char sA[2][8192];
    __shared__ alignas(16) char sB[2][8192];
    const int z = blockIdx.z;
    const unsigned short* W = (z == 0) ? wqb : (z == 1) ? wkb : wvb;
    const float* bias        = (z == 0) ? bq  : (z == 1) ? bk  : bv;
    float* Y                 = (z == 0) ? Qf  : (z == 1) ? Kf  : Vf;
    unsigned short* sec      = (z == 1) ? KbW : (z == 2) ? VtW : nullptr;
    gemm_body(xb, W, bias, Y, sec, z, blockIdx.y * 64, blockIdx.x * 64,
              sA[0], sA[1], sB[0], sB[1]);
}

// output projection (plain)
__global__ __launch_bounds__(256, 3) void gemm_out(
    const unsigned short* __restrict__ A,
    const unsigned short* __restrict__ W,
    const float* __restrict__ bias,
    float* __restrict__ Y)
{
    __shared__ alignas(16) char sA[2][8192];
    __shared__ alignas(16) char sB[2][8192];
    gemm_body(A, W, bias, Y, nullptr, 0, blockIdx.y * 64, blockIdx.x * 64,
              sA[0], sA[1], sB[0], sB[1]);
}

// ---------------------------------------------------------------------------
// fused attention == R12's verified 204.5us kernel, with ONE change:
// attn store is nontemporal (no L2 write-allocate -> staging reads keep L2).
// Block = 32 q-rows x 1 head, 4 waves, grid 1024, 4 blocks/CU (LDS 40960B,
// VGPR <= 128 via __launch_bounds__(256,4) -> 16 waves/CU).
// Wave w: row-group rg = w>>1 (16 rows), m-half mh = w&1 of each 128-m chunk.
// ---------------------------------------------------------------------------
__global__ __launch_bounds__(256, 4) void fused_attn(
    const float* __restrict__ Q,             // [TOK][EDIM] f32
    const unsigned short* __restrict__ Kb,   // [H][TOK][64] bf16
    const unsigned short* __restrict__ Vt,   // [H][64][TOK] bf16
    float* __restrict__ attn,                // [H][TOK][TOK] f32
    unsigned short* __restrict__ ctxb)       // [TOK][EDIM] bf16
{
    // pass1: K dbuf 2x16KB | pass2: sK 16KB + sV 16KB | epilogue: O partials
    __shared__ alignas(16) char lds_main[32768];
    __shared__ alignas(16) char ldsP[8192];     // 4 waves x [16 rows][128B] P tiles

    const int t = threadIdx.x;
    const int lane = t & 63, w = t >> 6;
    const int l15 = lane & 15, g4 = lane >> 4;
    const int bid = blockIdx.x;
    const int h  = bid & 7;                  // head-per-XCD L2 locality
    const int n0 = (bid >> 3) * 32;
    const int rg = w >> 1;                   // row-group (16 rows)
    const int mh = w & 1;                    // m-half of each 128-chunk
    const int xsw = (l15 & 7) << 1;          // P-LDS swizzle (8B-slot XOR)

    const unsigned short* KbH = Kb + (size_t)h * TOK * DHEAD;
    const unsigned short* VtH = Vt + (size_t)h * DHEAD * TOK;
    char* myP = ldsP + w * 2048;             // [16 rows][16 slot8] bf16
    float* redS = (float*)lds_main;          // [32 rows][2 halves] (transient)

    // ---- Q B-fragment for this wave's 16 rows (col n=l15, k d=g4*8+j) ----
    short8v bq[2];
    {
        const float* qp = Q + (size_t)(n0 + rg * 16 + l15) * EDIM + h * DHEAD + g4 * 8;
#pragma unroll
        for (int ks = 0; ks < 2; ++ks) {
            float4 u = *(const float4*)(qp + ks * 32);
            float4 v = *(const float4*)(qp + ks * 32 + 4);
            bq[ks][0] = (short)f2bf(u.x); bq[ks][1] = (short)f2bf(u.y);
            bq[ks][2] = (short)f2bf(u.z); bq[ks][3] = (short)f2bf(u.w);
            bq[ks][4] = (short)f2bf(v.x); bq[ks][5] = (short)f2bf(v.y);
            bq[ks][6] = (short)f2bf(v.z); bq[ks][7] = (short)f2bf(v.w);
        }
    }

    short8v kreg[4], vreg[4];
    // K chunk [128 m][64 d] staged by all 256 threads (4 x 16B each)
#define LK(c) { _Pragma("unroll") for (int j = 0; j < 4; ++j) { \
        const int unit_ = j * 256 + t, row_ = unit_ >> 3, u_ = unit_ & 7; \
        kreg[j] = *(const short8v*)(KbH + (size_t)((c) * 128 + row_) * 64 + u_ * 8); } }
#define WK(base) { _Pragma("unroll") for (int j = 0; j < 4; ++j) { \
        const int unit_ = j * 256 + t, row_ = unit_ >> 3, u_ = unit_ & 7; \
        *(short8v*)((base) + row_ * 128 + ((u_ ^ (row_ & 7)) * 16)) = kreg[j]; } }
    // V chunk [64 d][128 m]
#define LV(c) { _Pragma("unroll") for (int j = 0; j < 4; ++j) { \
        const int unit_ = j * 256 + t, row_ = unit_ >> 4, u_ = unit_ & 15; \
        vreg[j] = *(const short8v*)(VtH + (size_t)row_ * TOK + (c) * 128 + u_ * 8); } }
#define WV(base) { _Pragma("unroll") for (int j = 0; j < 4; ++j) { \
        const int unit_ = j * 256 + t, row_ = unit_ >> 4, u_ = unit_ & 15; \
        *(short8v*)((base) + row_ * 256 + ((u_ ^ (row_ & 7)) * 16)) = vreg[j]; } }

    // ================= pass 1: row sums (K dbuf, 1 soft barrier/chunk) =======
    float psum = 0.f;
    LK(0); WK(lds_main); __syncthreads();
    for (int c = 0; c < 32; ++c) {
        if (c < 31) LK(c + 1);
        const char* sKc = lds_main + (c & 1) * 16384;
#pragma unroll
        for (int mt = 0; mt < 4; ++mt) {
            const int row = mh * 64 + mt * 16 + l15;
            short8v k0 = *(const short8v*)(sKc + row * 128 + ((g4 ^ (l15 & 7)) * 16));
            short8v k1 = *(const short8v*)(sKc + row * 128 + (((4 + g4) ^ (l15 & 7)) * 16));
            __builtin_amdgcn_s_setprio(1);
            float4v s = (float4v){0.f, 0.f, 0.f, 0.f};
            s = __builtin_amdgcn_mfma_f32_16x16x32_bf16(k0, bq[0], s, 0, 0, 0);
            s = __builtin_amdgcn_mfma_f32_16x16x32_bf16(k1, bq[1], s, 0, 0, 0);
            __builtin_amdgcn_s_setprio(0);
#pragma unroll
            for (int r = 0; r < 4; ++r)
                psum += fast_exp2(s[r] * SC2);
        }
        if (c < 31) WK(lds_main + ((c + 1) & 1) * 16384);
        soft_barrier();
    }
    // reduce over g4 (lanes sharing row n), publish per (row, m-half)
    psum += __shfl_xor(psum, 16, 64);
    psum += __shfl_xor(psum, 32, 64);
    if (lane < 16)
        redS[(rg * 16 + lane) * 2 + mh] = psum;
    __syncthreads();
    const float inv = 1.0f / (redS[(rg * 16 + l15) * 2] + redS[(rg * 16 + l15) * 2 + 1]);
    __syncthreads();                          // redS consumed; lds_main reusable

    // ================= pass 2: attn store + PV =================
    float* aH = attn + ((size_t)h * TOK + n0 + rg * 16 + l15) * TOK;
    float4v cacc[4];
#pragma unroll
    for (int dt = 0; dt < 4; ++dt) cacc[dt] = (float4v){0.f, 0.f, 0.f, 0.f};

    char* sK2 = lds_main;
    char* sV2 = lds_main + 16384;

    LK(0); LV(0); WK(sK2); WV(sV2); __syncthreads();
    for (int c = 0; c < 32; ++c) {
        if (c < 31) { LK(c + 1); LV(c + 1); }
        const int mbase = c * 128 + mh * 64;
#pragma unroll
        for (int mt = 0; mt < 4; ++mt) {
            const int row = mh * 64 + mt * 16 + l15;
            short8v k0 = *(const short8v*)(sK2 + row * 128 + ((g4 ^ (l15 & 7)) * 16));
            short8v k1 = *(const short8v*)(sK2 + row * 128 + (((4 + g4) ^ (l15 & 7)) * 16));
            __builtin_amdgcn_s_setprio(1);
            float4v s = (float4v){0.f, 0.f, 0.f, 0.f};
            s = __builtin_amdgcn_mfma_f32_16x16x32_bf16(k0, bq[0], s, 0, 0, 0);
            s = __builtin_amdgcn_mfma_f32_16x16x32_bf16(k1, bq[1], s, 0, 0, 0);
            __builtin_amdgcn_s_setprio(0);
            float4v p;
#pragma unroll
            for (int r = 0; r < 4; ++r)
                p[r] = fast_exp2(s[r] * SC2) * inv;
            __builtin_nontemporal_store(
                p, (float4v*)(aH + mbase + mt * 16 + g4 * 4));   // NT store
            const unsigned int u0 = packbf_tr(p[0], p[1]);
            const unsigned int u1 = packbf_tr(p[2], p[3]);
            *(uint2*)(myP + l15 * 128 + (((mt * 4 + g4) ^ xsw) << 3)) =
                make_uint2(u0, u1);
        }
        // PV over this wave's 64-m half: A=P[n=l15][k], B=V[d][k]
        __builtin_amdgcn_s_setprio(1);
#pragma unroll
        for (int ks2 = 0; ks2 < 2; ++ks2) {
            const uint4v pr = *(const uint4v*)(myP + l15 * 128 +
                                               (((ks2 * 8 + g4 * 2) ^ xsw) << 3));
            const short8v pa = __builtin_bit_cast(short8v, pr);
#pragma unroll
            for (int dt = 0; dt < 4; ++dt) {
                const int rowv = dt * 16 + l15;
                const int uu = (mh * 8 + ks2 * 4 + g4) ^ (l15 & 7);
                short8v vf = *(const short8v*)(sV2 + rowv * 256 + uu * 16);
                cacc[dt] = __builtin_amdgcn_mfma_f32_16x16x32_bf16(pa, vf, cacc[dt], 0, 0, 0);
            }
        }
        __builtin_amdgcn_s_setprio(0);
        soft_barrier();
        if (c < 31) { WK(sK2); WV(sV2); soft_barrier(); }
    }

    // ---- pairwise cross-wave O reduction (lds_main free; stride-68 f32) ----
    __syncthreads();
    float* osh = (float*)lds_main + (size_t)w * 1088;   // [16 rows][68]
#pragma unroll
    for (int dt = 0; dt < 4; ++dt)
#pragma unroll
        for (int r = 0; r < 4; ++r)
            osh[(g4 * 4 + r) * 68 + dt * 16 + l15] = cacc[dt][r];
    __syncthreads();
    {
        const int n = t >> 3, dq = t & 7;               // 32 rows x 8 d-octets
        const int w0 = (n >> 4) * 2;                    // waves holding this row
        const float* o0 = (const float*)lds_main + (size_t)w0 * 1088 + (n & 15) * 68 + dq * 8;
        unsigned short ob[8];
#pragma unroll
        for (int q = 0; q < 2; ++q) {
            float4 s = *(const float4*)(o0 + q * 4);
            const float4 a = *(const float4*)(o0 + 1088 + q * 4);
            s.x += a.x; s.y += a.y; s.z += a.z; s.w += a.w;
            ob[q * 4 + 0] = f2bf(s.x); ob[q * 4 + 1] = f2bf(s.y);
            ob[q * 4 + 2] = f2bf(s.z); ob[q * 4 + 3] = f2bf(s.w);
        }
        *(short8v*)(ctxb + (size_t)(n0 + n) * EDIM + h * DHEAD + dq * 8) =
            *(const short8v*)&ob[0];
    }
#undef LK
#undef WK
#undef LV
#undef WV
}

// ---------------------------------------------------------------------------
// launch
// ---------------------------------------------------------------------------
extern "C" void kernel_launch(void* const* d_in, const int* in_sizes, int n_in,
                              void* d_out, int out_size, void* d_ws, size_t ws_size,
                              hipStream_t stream) {
    (void)in_sizes; (void)n_in; (void)out_size; (void)ws_size;

    const float* x  = (const float*)d_in[0];
    const float* Wq = (const float*)d_in[1];
    const float* bq = (const float*)d_in[2];
    const float* Wk = (const float*)d_in[3];
    const float* bk = (const float*)d_in[4];
    const float* Wv = (const float*)d_in[5];
    const float* bv = (const float*)d_in[6];
    const float* Wo = (const float*)d_in[7];
    const float* bo = (const float*)d_in[8];

    float* out  = (float*)d_out;                       // [TOK, EDIM]
    float* attn = out  + (size_t)TOK * EDIM;           // [H, TOK, TOK]
    float* Qf   = attn + (size_t)HEADS * TOK * TOK;    // [TOK, EDIM]
    float* Kf   = Qf   + (size_t)TOK * EDIM;
    float* Vf   = Kf   + (size_t)TOK * EDIM;

    char* wsb = (char*)d_ws;
    unsigned short* xb   = (unsigned short*)wsb;                     // 4 MB (reused as ctxb)
    unsigned short* wqb  = (unsigned short*)(wsb + (4u << 20));
    unsigned short* wkb  = (unsigned short*)(wsb + (4u << 20) + (512u << 10));
    unsigned short* wvb  = (unsigned short*)(wsb + (5u << 20));
    unsigned short* wob  = (unsigned short*)(wsb + (5u << 20) + (512u << 10));
    unsigned short* KbW  = (unsigned short*)(wsb + (6u << 20));      // 4 MB
    unsigned short* VtW  = (unsigned short*)(wsb + (10u << 20));     // 4 MB
    unsigned short* ctxb = xb;

    to_bf16_all<<<1536, 256, 0, stream>>>(x, Wq, Wk, Wv, Wo, xb, wqb, wkb, wvb, wob);

    dim3 gqkv(EDIM / 64, TOK / 64, 3);
    gemm_qkv<<<gqkv, 256, 0, stream>>>(xb, wqb, wkb, wvb, bq, bk, bv,
                                       Qf, Kf, Vf, KbW, VtW);

    fused_attn<<<1024, 256, 0, stream>>>(Qf, KbW, VtW, attn, ctxb);

    dim3 gl(EDIM / 64, TOK / 64);
    gemm_out<<<gl, 256, 0, stream>>>(ctxb, wob, bo, out);
}

// Round 15
// 202.109 us; speedup vs baseline: 1.3001x; 1.1346x over previous
//
#include <hip/hip_runtime.h>
#include <hip/hip_bf16.h>
#include <math.h>

#define TOK   4096
#define EDIM  512
#define HEADS 8
#define DHEAD 64

typedef __attribute__((ext_vector_type(8))) short short8v;
typedef __attribute__((ext_vector_type(4))) float float4v;
typedef __attribute__((ext_vector_type(4))) unsigned int uint4v;

#define SC2 0.180336880111f   /* 0.125 * log2(e) */

__device__ __forceinline__ unsigned short f2bf(float f) {
    unsigned int u = __float_as_uint(f);
    unsigned int r = (u + 0x7FFFu + ((u >> 16) & 1u)) >> 16;
    return (unsigned short)r;
}
// pack (truncating) bf16(lo) | bf16(hi)<<16 in one v_perm_b32
__device__ __forceinline__ unsigned int packbf_tr(float lo, float hi) {
    return __builtin_amdgcn_perm(__float_as_uint(hi), __float_as_uint(lo), 0x07060302u);
}
__device__ __forceinline__ float fast_exp2(float x) {
#if __has_builtin(__builtin_amdgcn_exp2f)
    return __builtin_amdgcn_exp2f(x);
#else
    return __expf(x * 0.69314718f);
#endif
}
// barrier with LDS-only drain: does NOT retire outstanding global stores/loads.
// 0xC07F = vmcnt(63) expcnt(7) lgkmcnt(0) on gfx9-encoding waitcnt.
__device__ __forceinline__ void soft_barrier() {
    __builtin_amdgcn_sched_barrier(0);
    __builtin_amdgcn_s_waitcnt(0xC07F);
    __builtin_amdgcn_s_barrier();
    __builtin_amdgcn_sched_barrier(0);
}

// ---------------------------------------------------------------------------
// prep: convert x and the 4 weight matrices to bf16 (one kernel).
// ---------------------------------------------------------------------------
__global__ __launch_bounds__(256) void to_bf16_all(
    const float* __restrict__ x,
    const float* __restrict__ wq, const float* __restrict__ wk,
    const float* __restrict__ wv, const float* __restrict__ wo,
    unsigned short* __restrict__ xb,
    unsigned short* __restrict__ wqb, unsigned short* __restrict__ wkb,
    unsigned short* __restrict__ wvb, unsigned short* __restrict__ wob)
{
    const int bid = blockIdx.x;
    const float* src; unsigned short* dst; int idx;
    if (bid < 1024) { src = x; dst = xb; idx = bid; }
    else {
        const int k = (bid - 1024) >> 7;
        idx = (bid - 1024) & 127;
        src = (k == 0) ? wq : (k == 1) ? wk : (k == 2) ? wv : wo;
        dst = (k == 0) ? wqb : (k == 1) ? wkb : (k == 2) ? wvb : wob;
    }
    const int off = idx * 2048 + threadIdx.x * 8;
    float4 a = *(const float4*)(src + off);
    float4 b = *(const float4*)(src + off + 4);
    short8v o;
    o[0] = (short)f2bf(a.x); o[1] = (short)f2bf(a.y);
    o[2] = (short)f2bf(a.z); o[3] = (short)f2bf(a.w);
    o[4] = (short)f2bf(b.x); o[5] = (short)f2bf(b.y);
    o[6] = (short)f2bf(b.z); o[7] = (short)f2bf(b.w);
    *(short8v*)(dst + off) = o;
}

// ---------------------------------------------------------------------------
// Shared GEMM body (verified R4-R14 structure): Y = A @ W^T + bias.
// mode 0: plain; 1: also bf16 sec[h][m][d]; 2: also bf16 sec[h][d][m].
// ---------------------------------------------------------------------------
__device__ __forceinline__ void gemm_body(
    const unsigned short* __restrict__ A,
    const unsigned short* __restrict__ W,
    const float* __restrict__ bias,
    float* __restrict__ Y,
    unsigned short* __restrict__ sec,
    int mode, int m0, int n0,
    char* sA0, char* sA1, char* sB0, char* sB1)
{
    const int t = threadIdx.x;
    const int lane = t & 63, w = t >> 6;
    const int l15 = lane & 15, g4 = lane >> 4;
    const int wr = w >> 1, wc = w & 1;

    short8v areg[2], breg[2];
    char* sA[2] = {sA0, sA1};
    char* sB[2] = {sB0, sB1};

#define GL(kk) { _Pragma("unroll") for (int j = 0; j < 2; ++j) { \
        const int unit_ = j * 256 + t, row_ = unit_ >> 3, u_ = unit_ & 7; \
        areg[j] = *(const short8v*)(A + (size_t)(m0 + row_) * 512 + (kk) * 64 + u_ * 8); \
        breg[j] = *(const short8v*)(W + (size_t)(n0 + row_) * 512 + (kk) * 64 + u_ * 8); } }
#define GW(b) { _Pragma("unroll") for (int j = 0; j < 2; ++j) { \
        const int unit_ = j * 256 + t, row_ = unit_ >> 3, u_ = unit_ & 7; \
        const int byt_ = row_ * 128 + ((u_ ^ (row_ & 7)) * 16); \
        *(short8v*)(sA[b] + byt_) = areg[j]; *(short8v*)(sB[b] + byt_) = breg[j]; } }

    float4v acc[2][2];
#pragma unroll
    for (int mi = 0; mi < 2; ++mi)
#pragma unroll
        for (int ni = 0; ni < 2; ++ni) acc[mi][ni] = (float4v){0.f, 0.f, 0.f, 0.f};

    GL(0); GW(0); __syncthreads();

#pragma unroll 2
    for (int kk = 0; kk < 8; ++kk) {
        if (kk < 7) GL(kk + 1);
        const char* cA = sA[kk & 1];
        const char* cB = sB[kk & 1];
        short8v af[2][2], bf[2][2];
#pragma unroll
        for (int mi = 0; mi < 2; ++mi)
#pragma unroll
            for (int kh = 0; kh < 2; ++kh) {
                const int row = wr * 32 + mi * 16 + l15;
                af[mi][kh] = *(const short8v*)(cA + row * 128 + (((kh * 4 + g4) ^ (l15 & 7)) * 16));
            }
#pragma unroll
        for (int ni = 0; ni < 2; ++ni)
#pragma unroll
            for (int kh = 0; kh < 2; ++kh) {
                const int row = wc * 32 + ni * 16 + l15;
                bf[ni][kh] = *(const short8v*)(cB + row * 128 + (((kh * 4 + g4) ^ (l15 & 7)) * 16));
            }
        __builtin_amdgcn_s_setprio(1);
#pragma unroll
        for (int mi = 0; mi < 2; ++mi)
#pragma unroll
            for (int ni = 0; ni < 2; ++ni) {
                acc[mi][ni] = __builtin_amdgcn_mfma_f32_16x16x32_bf16(af[mi][0], bf[ni][0], acc[mi][ni], 0, 0, 0);
                acc[mi][ni] = __builtin_amdgcn_mfma_f32_16x16x32_bf16(af[mi][1], bf[ni][1], acc[mi][ni], 0, 0, 0);
            }
        __builtin_amdgcn_s_setprio(0);
        if (kk < 7) GW((kk + 1) & 1);
        __syncthreads();
    }

#pragma unroll
    for (int mi = 0; mi < 2; ++mi)
#pragma unroll
        for (int ni = 0; ni < 2; ++ni) {
            const int col = n0 + wc * 32 + ni * 16 + l15;
            const float bb = bias[col];
#pragma unroll
            for (int r = 0; r < 4; ++r) {
                const int row = m0 + wr * 32 + mi * 16 + g4 * 4 + r;
                const float v = acc[mi][ni][r] + bb;
                Y[(size_t)row * 512 + col] = v;
                if (mode == 1)
                    sec[((size_t)(col >> 6) * TOK + row) * 64 + (col & 63)] = f2bf(v);
                else if (mode == 2)
                    sec[((size_t)(col >> 6) * 64 + (col & 63)) * TOK + row] = f2bf(v);
            }
        }
#undef GL
#undef GW
}

// ---------------------------------------------------------------------------
// merged Q/K/V projection: blockIdx.z selects which of the three GEMMs.
// 1536 blocks resident at once (vs 3 serial 512-block launches).
// ---------------------------------------------------------------------------
__global__ __launch_bounds__(256, 3) void gemm_qkv(
    const unsigned short* __restrict__ xb,
    const unsigned short* __restrict__ wqb,
    const unsigned short* __restrict__ wkb,
    const unsigned short* __restrict__ wvb,
    const float* __restrict__ bq, const float* __restrict__ bk,
    const float* __restrict__ bv,
    float* __restrict__ Qf, float* __restrict__ Kf, float* __restrict__ Vf,
    unsigned short* __restrict__ KbW, unsigned short* __restrict__ VtW)
{
    __shared__ alignas(16) char sA[2][8192];
    __shared__ alignas(16) char sB[2][8192];
    const int z = blockIdx.z;
    const unsigned short* W = (z == 0) ? wqb : (z == 1) ? wkb : wvb;
    const float* bias        = (z == 0) ? bq  : (z == 1) ? bk  : bv;
    float* Y                 = (z == 0) ? Qf  : (z == 1) ? Kf  : Vf;
    unsigned short* sec      = (z == 1) ? KbW : (z == 2) ? VtW : nullptr;
    gemm_body(xb, W, bias, Y, sec, z, blockIdx.y * 64, blockIdx.x * 64,
              sA[0], sA[1], sB[0], sB[1]);
}

// output projection (plain)
__global__ __launch_bounds__(256, 3) void gemm_out(
    const unsigned short* __restrict__ A,
    const unsigned short* __restrict__ W,
    const float* __restrict__ bias,
    float* __restrict__ Y)
{
    __shared__ alignas(16) char sA[2][8192];
    __shared__ alignas(16) char sB[2][8192];
    gemm_body(A, W, bias, Y, nullptr, 0, blockIdx.y * 64, blockIdx.x * 64,
              sA[0], sA[1], sB[0], sB[1]);
}

// ---------------------------------------------------------------------------
// fused attention == R12's verified 204.5us kernel, bit-identical (plain
// float4 attn stores restored; the R14 NT-store experiment cost ~25us).
// Block = 32 q-rows x 1 head, 4 waves, grid 1024, 4 blocks/CU (LDS 40960B,
// VGPR <= 128 via __launch_bounds__(256,4) -> 16 waves/CU).
// Wave w: row-group rg = w>>1 (16 rows), m-half mh = w&1 of each 128-m chunk.
// ---------------------------------------------------------------------------
__global__ __launch_bounds__(256, 4) void fused_attn(
    const float* __restrict__ Q,             // [TOK][EDIM] f32
    const unsigned short* __restrict__ Kb,   // [H][TOK][64] bf16
    const unsigned short* __restrict__ Vt,   // [H][64][TOK] bf16
    float* __restrict__ attn,                // [H][TOK][TOK] f32
    unsigned short* __restrict__ ctxb)       // [TOK][EDIM] bf16
{
    // pass1: K dbuf 2x16KB | pass2: sK 16KB + sV 16KB | epilogue: O partials
    __shared__ alignas(16) char lds_main[32768];
    __shared__ alignas(16) char ldsP[8192];     // 4 waves x [16 rows][128B] P tiles

    const int t = threadIdx.x;
    const int lane = t & 63, w = t >> 6;
    const int l15 = lane & 15, g4 = lane >> 4;
    const int bid = blockIdx.x;
    const int h  = bid & 7;                  // head-per-XCD L2 locality
    const int n0 = (bid >> 3) * 32;
    const int rg = w >> 1;                   // row-group (16 rows)
    const int mh = w & 1;                    // m-half of each 128-chunk
    const int xsw = (l15 & 7) << 1;          // P-LDS swizzle (8B-slot XOR)

    const unsigned short* KbH = Kb + (size_t)h * TOK * DHEAD;
    const unsigned short* VtH = Vt + (size_t)h * DHEAD * TOK;
    char* myP = ldsP + w * 2048;             // [16 rows][16 slot8] bf16
    float* redS = (float*)lds_main;          // [32 rows][2 halves] (transient)

    // ---- Q B-fragment for this wave's 16 rows (col n=l15, k d=g4*8+j) ----
    short8v bq[2];
    {
        const float* qp = Q + (size_t)(n0 + rg * 16 + l15) * EDIM + h * DHEAD + g4 * 8;
#pragma unroll
        for (int ks = 0; ks < 2; ++ks) {
            float4 u = *(const float4*)(qp + ks * 32);
            float4 v = *(const float4*)(qp + ks * 32 + 4);
            bq[ks][0] = (short)f2bf(u.x); bq[ks][1] = (short)f2bf(u.y);
            bq[ks][2] = (short)f2bf(u.z); bq[ks][3] = (short)f2bf(u.w);
            bq[ks][4] = (short)f2bf(v.x); bq[ks][5] = (short)f2bf(v.y);
            bq[ks][6] = (short)f2bf(v.z); bq[ks][7] = (short)f2bf(v.w);
        }
    }

    short8v kreg[4], vreg[4];
    // K chunk [128 m][64 d] staged by all 256 threads (4 x 16B each)
#define LK(c) { _Pragma("unroll") for (int j = 0; j < 4; ++j) { \
        const int unit_ = j * 256 + t, row_ = unit_ >> 3, u_ = unit_ & 7; \
        kreg[j] = *(const short8v*)(KbH + (size_t)((c) * 128 + row_) * 64 + u_ * 8); } }
#define WK(base) { _Pragma("unroll") for (int j = 0; j < 4; ++j) { \
        const int unit_ = j * 256 + t, row_ = unit_ >> 3, u_ = unit_ & 7; \
        *(short8v*)((base) + row_ * 128 + ((u_ ^ (row_ & 7)) * 16)) = kreg[j]; } }
    // V chunk [64 d][128 m]
#define LV(c) { _Pragma("unroll") for (int j = 0; j < 4; ++j) { \
        const int unit_ = j * 256 + t, row_ = unit_ >> 4, u_ = unit_ & 15; \
        vreg[j] = *(const short8v*)(VtH + (size_t)row_ * TOK + (c) * 128 + u_ * 8); } }
#define WV(base) { _Pragma("unroll") for (int j = 0; j < 4; ++j) { \
        const int unit_ = j * 256 + t, row_ = unit_ >> 4, u_ = unit_ & 15; \
        *(short8v*)((base) + row_ * 256 + ((u_ ^ (row_ & 7)) * 16)) = vreg[j]; } }

    // ================= pass 1: row sums (K dbuf, 1 soft barrier/chunk) =======
    float psum = 0.f;
    LK(0); WK(lds_main); __syncthreads();
    for (int c = 0; c < 32; ++c) {
        if (c < 31) LK(c + 1);
        const char* sKc = lds_main + (c & 1) * 16384;
#pragma unroll
        for (int mt = 0; mt < 4; ++mt) {
            const int row = mh * 64 + mt * 16 + l15;
            short8v k0 = *(const short8v*)(sKc + row * 128 + ((g4 ^ (l15 & 7)) * 16));
            short8v k1 = *(const short8v*)(sKc + row * 128 + (((4 + g4) ^ (l15 & 7)) * 16));
            __builtin_amdgcn_s_setprio(1);
            float4v s = (float4v){0.f, 0.f, 0.f, 0.f};
            s = __builtin_amdgcn_mfma_f32_16x16x32_bf16(k0, bq[0], s, 0, 0, 0);
            s = __builtin_amdgcn_mfma_f32_16x16x32_bf16(k1, bq[1], s, 0, 0, 0);
            __builtin_amdgcn_s_setprio(0);
#pragma unroll
            for (int r = 0; r < 4; ++r)
                psum += fast_exp2(s[r] * SC2);
        }
        if (c < 31) WK(lds_main + ((c + 1) & 1) * 16384);
        soft_barrier();
    }
    // reduce over g4 (lanes sharing row n), publish per (row, m-half)
    psum += __shfl_xor(psum, 16, 64);
    psum += __shfl_xor(psum, 32, 64);
    if (lane < 16)
        redS[(rg * 16 + lane) * 2 + mh] = psum;
    __syncthreads();
    const float inv = 1.0f / (redS[(rg * 16 + l15) * 2] + redS[(rg * 16 + l15) * 2 + 1]);
    __syncthreads();                          // redS consumed; lds_main reusable

    // ================= pass 2: attn store + PV =================
    float* aH = attn + ((size_t)h * TOK + n0 + rg * 16 + l15) * TOK;
    float4v cacc[4];
#pragma unroll
    for (int dt = 0; dt < 4; ++dt) cacc[dt] = (float4v){0.f, 0.f, 0.f, 0.f};

    char* sK2 = lds_main;
    char* sV2 = lds_main + 16384;

    LK(0); LV(0); WK(sK2); WV(sV2); __syncthreads();
    for (int c = 0; c < 32; ++c) {
        if (c < 31) { LK(c + 1); LV(c + 1); }
        const int mbase = c * 128 + mh * 64;
#pragma unroll
        for (int mt = 0; mt < 4; ++mt) {
            const int row = mh * 64 + mt * 16 + l15;
            short8v k0 = *(const short8v*)(sK2 + row * 128 + ((g4 ^ (l15 & 7)) * 16));
            short8v k1 = *(const short8v*)(sK2 + row * 128 + (((4 + g4) ^ (l15 & 7)) * 16));
            __builtin_amdgcn_s_setprio(1);
            float4v s = (float4v){0.f, 0.f, 0.f, 0.f};
            s = __builtin_amdgcn_mfma_f32_16x16x32_bf16(k0, bq[0], s, 0, 0, 0);
            s = __builtin_amdgcn_mfma_f32_16x16x32_bf16(k1, bq[1], s, 0, 0, 0);
            __builtin_amdgcn_s_setprio(0);
            float4v p;
#pragma unroll
            for (int r = 0; r < 4; ++r)
                p[r] = fast_exp2(s[r] * SC2) * inv;
            *(float4v*)(aH + mbase + mt * 16 + g4 * 4) = p;   // plain store
            const unsigned int u0 = packbf_tr(p[0], p[1]);
            const unsigned int u1 = packbf_tr(p[2], p[3]);
            *(uint2*)(myP + l15 * 128 + (((mt * 4 + g4) ^ xsw) << 3)) =
                make_uint2(u0, u1);
        }
        // PV over this wave's 64-m half: A=P[n=l15][k], B=V[d][k]
        __builtin_amdgcn_s_setprio(1);
#pragma unroll
        for (int ks2 = 0; ks2 < 2; ++ks2) {
            const uint4v pr = *(const uint4v*)(myP + l15 * 128 +
                                               (((ks2 * 8 + g4 * 2) ^ xsw) << 3));
            const short8v pa = __builtin_bit_cast(short8v, pr);
#pragma unroll
            for (int dt = 0; dt < 4; ++dt) {
                const int rowv = dt * 16 + l15;
                const int uu = (mh * 8 + ks2 * 4 + g4) ^ (l15 & 7);
                short8v vf = *(const short8v*)(sV2 + rowv * 256 + uu * 16);
                cacc[dt] = __builtin_amdgcn_mfma_f32_16x16x32_bf16(pa, vf, cacc[dt], 0, 0, 0);
            }
        }
        __builtin_amdgcn_s_setprio(0);
        soft_barrier();
        if (c < 31) { WK(sK2); WV(sV2); soft_barrier(); }
    }

    // ---- pairwise cross-wave O reduction (lds_main free; stride-68 f32) ----
    __syncthreads();
    float* osh = (float*)lds_main + (size_t)w * 1088;   // [16 rows][68]
#pragma unroll
    for (int dt = 0; dt < 4; ++dt)
#pragma unroll
        for (int r = 0; r < 4; ++r)
            osh[(g4 * 4 + r) * 68 + dt * 16 + l15] = cacc[dt][r];
    __syncthreads();
    {
        const int n = t >> 3, dq = t & 7;               // 32 rows x 8 d-octets
        const int w0 = (n >> 4) * 2;                    // waves holding this row
        const float* o0 = (const float*)lds_main + (size_t)w0 * 1088 + (n & 15) * 68 + dq * 8;
        unsigned short ob[8];
#pragma unroll
        for (int q = 0; q < 2; ++q) {
            float4 s = *(const float4*)(o0 + q * 4);
            const float4 a = *(const float4*)(o0 + 1088 + q * 4);
            s.x += a.x; s.y += a.y; s.z += a.z; s.w += a.w;
            ob[q * 4 + 0] = f2bf(s.x); ob[q * 4 + 1] = f2bf(s.y);
            ob[q * 4 + 2] = f2bf(s.z); ob[q * 4 + 3] = f2bf(s.w);
        }
        *(short8v*)(ctxb + (size_t)(n0 + n) * EDIM + h * DHEAD + dq * 8) =
            *(const short8v*)&ob[0];
    }
#undef LK
#undef WK
#undef LV
#undef WV
}

// ---------------------------------------------------------------------------
// launch
// ---------------------------------------------------------------------------
extern "C" void kernel_launch(void* const* d_in, const int* in_sizes, int n_in,
                              void* d_out, int out_size, void* d_ws, size_t ws_size,
                              hipStream_t stream) {
    (void)in_sizes; (void)n_in; (void)out_size; (void)ws_size;

    const float* x  = (const float*)d_in[0];
    const float* Wq = (const float*)d_in[1];
    const float* bq = (const float*)d_in[2];
    const float* Wk = (const float*)d_in[3];
    const float* bk = (const float*)d_in[4];
    const float* Wv = (const float*)d_in[5];
    const float* bv = (const float*)d_in[6];
    const float* Wo = (const float*)d_in[7];
    const float* bo = (const float*)d_in[8];

    float* out  = (float*)d_out;                       // [TOK, EDIM]
    float* attn = out  + (size_t)TOK * EDIM;           // [H, TOK, TOK]
    float* Qf   = attn + (size_t)HEADS * TOK * TOK;    // [TOK, EDIM]
    float* Kf   = Qf   + (size_t)TOK * EDIM;
    float* Vf   = Kf   + (size_t)TOK * EDIM;

    char* wsb = (char*)d_ws;
    unsigned short* xb   = (unsigned short*)wsb;                     // 4 MB (reused as ctxb)
    unsigned short* wqb  = (unsigned short*)(wsb + (4u << 20));
    unsigned short* wkb  = (unsigned short*)(wsb + (4u << 20) + (512u << 10));
    unsigned short* wvb  = (unsigned short*)(wsb + (5u << 20));
    unsigned short* wob  = (unsigned short*)(wsb + (5u << 20) + (512u << 10));
    unsigned short* KbW  = (unsigned short*)(wsb + (6u << 20));      // 4 MB
    unsigned short* VtW  = (unsigned short*)(wsb + (10u << 20));     // 4 MB
    unsigned short* ctxb = xb;

    to_bf16_all<<<1536, 256, 0, stream>>>(x, Wq, Wk, Wv, Wo, xb, wqb, wkb, wvb, wob);

    dim3 gqkv(EDIM / 64, TOK / 64, 3);
    gemm_qkv<<<gqkv, 256, 0, stream>>>(xb, wqb, wkb, wvb, bq, bk, bv,
                                       Qf, Kf, Vf, KbW, VtW);

    fused_attn<<<1024, 256, 0, stream>>>(Qf, KbW, VtW, attn, ctxb);

    dim3 gl(EDIM / 64, TOK / 64);
    gemm_out<<<gl, 256, 0, stream>>>(ctxb, wob, bo, out);
}